// Round 2
// baseline (1821.777 us; speedup 1.0000x reference)
//
#include <hip/hip_runtime.h>
#include <hip/hip_bf16.h>
#include <cstdint>
#include <cstddef>

#define NE  16
#define HD  1024
#define ID  4096
#define TPE 2048
#define MBLK 128
#define NMB_TOTAL (NE * (TPE / MBLK))   // 256 M-blocks of 128 tokens

typedef __attribute__((ext_vector_type(8))) short short8;     // 8 bf16 (4 VGPRs)
typedef __attribute__((ext_vector_type(4))) float f32x4;      // MFMA acc
typedef __attribute__((ext_vector_type(4))) unsigned int u32x4;
typedef __attribute__((ext_vector_type(4))) unsigned short u16x4;

static __device__ __forceinline__ unsigned short f2b(float f) {
    __bf16 h = (__bf16)f;                       // RNE fp32->bf16
    return __builtin_bit_cast(unsigned short, h);
}

static __device__ __forceinline__ float fcomp(const float4& v, int j) {
    return j == 0 ? v.x : j == 1 ? v.y : j == 2 ? v.z : v.w;   // j is const after unroll
}

// ---------------------------------------------------------------------------
// GEMM1 + SwiGLU: x[mb](128 x 1024) @ gate_up[e](1024 x 8192) -> gated bf16
// Block tile: 128 rows x 64 gated cols (gate half + up half).
// A in LDS: [row][k] bf16, 16B slots XOR-swizzled by row&7.
// B in LDS: [c][k]  bf16 (transposed at staging), same swizzle by c&7.
// Both fragments read with ds_read_b128 (8 contiguous k per lane) -> any HW
// intra-lane k-permutation applies identically to A and B (safe).
// ---------------------------------------------------------------------------
__global__ __launch_bounds__(256) void k_gemm1(const float* __restrict__ hs,
                                               const float* __restrict__ gup,
                                               unsigned short* __restrict__ gated,
                                               int b0)
{
    __shared__ unsigned short As[128 * 64];
    __shared__ unsigned short Bs[128 * 64];   // c: 0-63 gate, 64-127 up

    const int t    = threadIdx.x;
    const int lane = t & 63;
    const int w    = t >> 6;
    const int wr   = w >> 1;
    const int wc   = w & 1;
    const int mb   = b0 + blockIdx.y;
    const int e    = mb >> 4;
    const int m0   = (mb & 15) * MBLK;
    const int n0   = blockIdx.x * 64;

    const float* gA = hs  + (size_t)(e * TPE + m0) * HD;
    const float* gB = gup + (size_t)e * HD * (2 * ID);

    f32x4 acc[4][4];   // [fm][q]: q=0,1 gate fn=0,1 ; q=2,3 up fn=0,1
    #pragma unroll
    for (int i = 0; i < 4; ++i)
        #pragma unroll
        for (int j = 0; j < 4; ++j)
            acc[i][j] = f32x4{0.f, 0.f, 0.f, 0.f};

    for (int kt = 0; kt < HD / 64; ++kt) {
        // ---- stage A: 128x64 fp32 -> bf16, swizzled ----
        const float* a0 = gA + kt * 64;
        #pragma unroll
        for (int i = 0; i < 8; ++i) {
            int idx = i * 256 + t;
            int row = idx >> 4;            // 16 threads per row, 256B coalesced
            int kq  = (idx & 15) << 2;
            float4 v = *(const float4*)(a0 + (size_t)row * HD + kq);
            u16x4 b4 = { f2b(v.x), f2b(v.y), f2b(v.z), f2b(v.w) };
            *(u16x4*)&As[row * 64 + (((kq >> 3) ^ (row & 7)) << 3) + (kq & 7)] = b4;
        }
        // ---- stage B transposed: 4k x 4c blocks per thread, 2 iterations ----
        const float* brow = gB + (size_t)(kt * 64) * (2 * ID);
        #pragma unroll
        for (int i = 0; i < 2; ++i) {
            int cg = t & 31;               // 32 col-groups of 4 (0-15 gate, 16-31 up)
            int kg = (t >> 5) + i * 8;     // 16 k-groups of 4
            int gc = (cg < 16) ? (n0 + cg * 4) : (ID + n0 + (cg - 16) * 4);
            int kb = kg * 4;
            float4 r0 = *(const float4*)(brow + (size_t)(kb + 0) * (2 * ID) + gc);
            float4 r1 = *(const float4*)(brow + (size_t)(kb + 1) * (2 * ID) + gc);
            float4 r2 = *(const float4*)(brow + (size_t)(kb + 2) * (2 * ID) + gc);
            float4 r3 = *(const float4*)(brow + (size_t)(kb + 3) * (2 * ID) + gc);
            #pragma unroll
            for (int j = 0; j < 4; ++j) {
                int c = cg * 4 + j;
                u16x4 b4 = { f2b(fcomp(r0, j)), f2b(fcomp(r1, j)),
                             f2b(fcomp(r2, j)), f2b(fcomp(r3, j)) };
                *(u16x4*)&Bs[c * 64 + (((kb >> 3) ^ (c & 7)) << 3) + (kb & 7)] = b4;
            }
        }
        __syncthreads();

        #pragma unroll
        for (int ks = 0; ks < 64; ks += 32) {
            const int sl = (ks >> 3) + (lane >> 4);
            short8 av[4], bv[4];
            #pragma unroll
            for (int fm = 0; fm < 4; ++fm) {
                int row = wr * 64 + fm * 16 + (lane & 15);
                av[fm] = *(const short8*)&As[row * 64 + ((sl ^ (row & 7)) << 3)];
            }
            #pragma unroll
            for (int q = 0; q < 4; ++q) {
                int c = ((q < 2) ? 0 : 64) + wc * 32 + (q & 1) * 16 + (lane & 15);
                bv[q] = *(const short8*)&Bs[c * 64 + ((sl ^ (c & 7)) << 3)];
            }
            #pragma unroll
            for (int fm = 0; fm < 4; ++fm)
                #pragma unroll
                for (int q = 0; q < 4; ++q)
                    acc[fm][q] = __builtin_amdgcn_mfma_f32_16x16x32_bf16(av[fm], bv[q], acc[fm][q], 0, 0, 0);
        }
        __syncthreads();
    }

    // ---- SwiGLU epilogue: gated = up * gate * sigmoid(gate), bf16 to ws ----
    unsigned short* g0 = gated + (size_t)blockIdx.y * (MBLK * ID);
    const int rq = (lane >> 4) << 2;   // C/D: row=(lane>>4)*4+r, col=lane&15 (m89)
    const int cl = lane & 15;
    #pragma unroll
    for (int fm = 0; fm < 4; ++fm) {
        #pragma unroll
        for (int fn = 0; fn < 2; ++fn) {
            f32x4 g = acc[fm][fn];
            f32x4 u = acc[fm][fn + 2];
            #pragma unroll
            for (int r = 0; r < 4; ++r) {
                float gv  = g[r];
                float val = u[r] * gv / (1.0f + __expf(-gv));
                int row = wr * 64 + fm * 16 + rq + r;
                int col = n0 + wc * 32 + fn * 16 + cl;
                g0[(size_t)row * ID + col] = f2b(val);
            }
        }
    }
}

// ---------------------------------------------------------------------------
// GEMM2: gated[mb](128 x 4096 bf16) @ down[e](4096 x 1024 fp32) -> out fp32
// ---------------------------------------------------------------------------
__global__ __launch_bounds__(256) void k_gemm2(const unsigned short* __restrict__ gated,
                                               const float* __restrict__ dwn,
                                               float* __restrict__ out,
                                               int b0)
{
    __shared__ unsigned short As[128 * 64];
    __shared__ unsigned short Bs[64 * 64];

    const int t    = threadIdx.x;
    const int lane = t & 63;
    const int w    = t >> 6;
    const int wr   = w >> 1;
    const int wc   = w & 1;
    const int mb   = b0 + blockIdx.y;
    const int e    = mb >> 4;
    const int m0   = (mb & 15) * MBLK;
    const int n0   = blockIdx.x * 64;

    const unsigned short* gA = gated + (size_t)blockIdx.y * (MBLK * ID);
    const float* gB = dwn + (size_t)e * ID * HD;

    f32x4 acc[4][2];
    #pragma unroll
    for (int i = 0; i < 4; ++i)
        #pragma unroll
        for (int j = 0; j < 2; ++j)
            acc[i][j] = f32x4{0.f, 0.f, 0.f, 0.f};

    for (int kt = 0; kt < ID / 64; ++kt) {
        // ---- stage A: 128x64 bf16, 16B vector copies, swizzled ----
        #pragma unroll
        for (int i = 0; i < 4; ++i) {
            int idx  = i * 256 + t;
            int row  = idx >> 3;
            int slot = idx & 7;
            u32x4 v = *(const u32x4*)(gA + (size_t)row * ID + kt * 64 + slot * 8);
            *(u32x4*)&As[row * 64 + ((slot ^ (row & 7)) << 3)] = v;
        }
        // ---- stage B transposed: 4k x 4c block per thread ----
        const float* brow = gB + (size_t)(kt * 64) * HD + n0;
        {
            int cg = t & 15;               // 16 col-groups of 4
            int kg = t >> 4;               // 16 k-groups of 4
            int kb = kg * 4;
            float4 r0 = *(const float4*)(brow + (size_t)(kb + 0) * HD + cg * 4);
            float4 r1 = *(const float4*)(brow + (size_t)(kb + 1) * HD + cg * 4);
            float4 r2 = *(const float4*)(brow + (size_t)(kb + 2) * HD + cg * 4);
            float4 r3 = *(const float4*)(brow + (size_t)(kb + 3) * HD + cg * 4);
            #pragma unroll
            for (int j = 0; j < 4; ++j) {
                int c = cg * 4 + j;
                u16x4 b4 = { f2b(fcomp(r0, j)), f2b(fcomp(r1, j)),
                             f2b(fcomp(r2, j)), f2b(fcomp(r3, j)) };
                *(u16x4*)&Bs[c * 64 + (((kb >> 3) ^ (c & 7)) << 3) + (kb & 7)] = b4;
            }
        }
        __syncthreads();

        #pragma unroll
        for (int ks = 0; ks < 64; ks += 32) {
            const int sl = (ks >> 3) + (lane >> 4);
            short8 av[4], bv[2];
            #pragma unroll
            for (int fm = 0; fm < 4; ++fm) {
                int row = wr * 64 + fm * 16 + (lane & 15);
                av[fm] = *(const short8*)&As[row * 64 + ((sl ^ (row & 7)) << 3)];
            }
            #pragma unroll
            for (int q = 0; q < 2; ++q) {
                int c = wc * 32 + q * 16 + (lane & 15);
                bv[q] = *(const short8*)&Bs[c * 64 + ((sl ^ (c & 7)) << 3)];
            }
            #pragma unroll
            for (int fm = 0; fm < 4; ++fm)
                #pragma unroll
                for (int q = 0; q < 2; ++q)
                    acc[fm][q] = __builtin_amdgcn_mfma_f32_16x16x32_bf16(av[fm], bv[q], acc[fm][q], 0, 0, 0);
        }
        __syncthreads();
    }

    // ---- epilogue: fp32 store ----
    float* o0 = out + (size_t)(e * TPE + m0) * HD;
    const int rq = (lane >> 4) << 2;
    const int cl = lane & 15;
    #pragma unroll
    for (int fm = 0; fm < 4; ++fm) {
        #pragma unroll
        for (int fn = 0; fn < 2; ++fn) {
            #pragma unroll
            for (int r = 0; r < 4; ++r) {
                int row = wr * 64 + fm * 16 + rq + r;
                int col = n0 + wc * 32 + fn * 16 + cl;
                o0[(size_t)row * HD + col] = acc[fm][fn][r];
            }
        }
    }
}

extern "C" void kernel_launch(void* const* d_in, const int* in_sizes, int n_in,
                              void* d_out, int out_size, void* d_ws, size_t ws_size,
                              hipStream_t stream)
{
    (void)in_sizes; (void)n_in; (void)out_size;
    const float* hs  = (const float*)d_in[0];
    const float* gup = (const float*)d_in[1];
    const float* dwn = (const float*)d_in[2];
    float* out = (float*)d_out;
    unsigned short* gated = (unsigned short*)d_ws;

    // gated scratch: 1 MB per 128-token M-block; chunk to fit ws_size.
    const size_t perMB = (size_t)MBLK * ID * sizeof(unsigned short);
    int chunk = (int)(ws_size / perMB);
    if (chunk < 1) chunk = 1;
    if (chunk > NMB_TOTAL) chunk = NMB_TOTAL;

    for (int b0 = 0; b0 < NMB_TOTAL; b0 += chunk) {
        int nb = NMB_TOTAL - b0;
        if (nb > chunk) nb = chunk;
        k_gemm1<<<dim3(ID / 64, nb), 256, 0, stream>>>(hs, gup, gated, b0);
        k_gemm2<<<dim3(HD / 64, nb), 256, 0, stream>>>(gated, dwn, out, b0);
    }
}

// Round 3
// 1460.441 us; speedup vs baseline: 1.2474x; 1.2474x over previous
//
#include <hip/hip_runtime.h>
#include <hip/hip_bf16.h>
#include <cstdint>
#include <cstddef>

#define NE  16
#define HD  1024
#define ID  4096
#define TPE 2048
#define TOKENS 32768

typedef __attribute__((ext_vector_type(8))) short short8;     // 8 bf16 (4 VGPRs)
typedef __attribute__((ext_vector_type(4))) float f32x4;      // MFMA acc
typedef __attribute__((ext_vector_type(4))) unsigned short u16x4;
typedef __attribute__((ext_vector_type(8))) unsigned short u16x8;

static __device__ __forceinline__ unsigned short f2b(float f) {
    __bf16 h = (__bf16)f;                       // RNE fp32->bf16
    return __builtin_bit_cast(unsigned short, h);
}

// wave-level async global->LDS, 16B per lane; lds base must be wave-uniform,
// HW writes base + lane*16 (linear). Swizzle is applied on the GLOBAL source
// (rule #21: linear dest + inverse-swz source + swz on read).
#define GLOAD16(gsrc, ldsbase)                                                  \
    __builtin_amdgcn_global_load_lds(                                           \
        (const __attribute__((address_space(1))) unsigned int*)(gsrc),          \
        (__attribute__((address_space(3))) unsigned int*)(ldsbase), 16, 0, 0)

// ---------------------------------------------------------------------------
// Pre-pass 1: hs fp32 -> bf16 (linear)
// ---------------------------------------------------------------------------
__global__ void k_f2b(const float* __restrict__ src, unsigned short* __restrict__ dst, int n4)
{
    int i = blockIdx.x * blockDim.x + threadIdx.x;
    int stride = gridDim.x * blockDim.x;
    for (; i < n4; i += stride) {
        float4 v = *(const float4*)(src + (size_t)i * 4);
        u16x4 b = { f2b(v.x), f2b(v.y), f2b(v.z), f2b(v.w) };
        *(u16x4*)(dst + (size_t)i * 4) = b;
    }
}

// ---------------------------------------------------------------------------
// Pre-pass 2: weight convert+transpose. src fp32 [e][K][N] (global e),
// dst bf16 [eL][N][K] (chunk-local). 64x64 tiles via LDS.
// ---------------------------------------------------------------------------
__global__ __launch_bounds__(256) void k_transpose(const float* __restrict__ src,
                                                   unsigned short* __restrict__ dst,
                                                   int K, int N, int e0)
{
    __shared__ unsigned short LT[64][72];   // [n][k], stride 144B (16B-aligned)
    const int t  = threadIdx.x;
    const int eL = blockIdx.z;
    const float* s = src + (size_t)(e0 + eL) * K * N
                         + (size_t)(blockIdx.y * 64) * N + blockIdx.x * 64;
    unsigned short* d = dst + (size_t)eL * N * K
                            + (size_t)(blockIdx.x * 64) * K + blockIdx.y * 64;
    #pragma unroll
    for (int i = 0; i < 4; ++i) {
        int row = i * 16 + (t >> 4);
        int c4  = (t & 15) * 4;
        float4 v = *(const float4*)(s + (size_t)row * N + c4);
        LT[c4 + 0][row] = f2b(v.x);
        LT[c4 + 1][row] = f2b(v.y);
        LT[c4 + 2][row] = f2b(v.z);
        LT[c4 + 3][row] = f2b(v.w);
    }
    __syncthreads();
    #pragma unroll
    for (int i = 0; i < 2; ++i) {
        int n  = i * 32 + (t >> 3);
        int k8 = (t & 7) * 8;
        u16x8 v = *(const u16x8*)&LT[n][k8];
        *(u16x8*)(d + (size_t)n * K + k8) = v;
    }
}

// ---------------------------------------------------------------------------
// GEMM1 + SwiGLU: hsB[mb](128 x 1024 bf16) @ gupT (k-contig bf16) -> gated bf16
// A LDS: [row][k] 16B slots; B LDS: [c][k] (c: 0-63 gate, 64-127 up).
// Staging via global_load_lds: linear LDS dest, source slot pre-swizzled so a
// read at slot (sl ^ (row&7)) returns global slot sl (same involution as r2).
// Fragment reads + MFMA + epilogue byte-identical to the round-2 passing code.
// ---------------------------------------------------------------------------
__global__ __launch_bounds__(256) void k_gemm1(const unsigned short* __restrict__ hsB,
                                               const unsigned short* __restrict__ gupT,
                                               unsigned short* __restrict__ gated,
                                               int e0)
{
    __shared__ unsigned short As[128 * 64];
    __shared__ unsigned short Bs[128 * 64];

    const int t    = threadIdx.x;
    const int lane = t & 63;
    const int w    = t >> 6;
    const int wr   = w >> 1;
    const int wc   = w & 1;
    const int eL   = blockIdx.z;
    const int e    = e0 + eL;
    const int n0   = blockIdx.x * 64;
    const int m0   = blockIdx.y * 128;

    const unsigned short* gA  = hsB  + (size_t)(e * TPE + m0) * HD;
    const unsigned short* gBt = gupT + (size_t)eL * (2 * ID) * HD;

    f32x4 acc[4][4];   // [fm][q]: q=0,1 gate ; q=2,3 up
    #pragma unroll
    for (int i = 0; i < 4; ++i)
        #pragma unroll
        for (int j = 0; j < 4; ++j)
            acc[i][j] = f32x4{0.f, 0.f, 0.f, 0.f};

    for (int kt = 0; kt < HD / 64; ++kt) {
        #pragma unroll
        for (int i = 0; i < 4; ++i) {           // A: 128 rows x 64 k
            int idx = i * 256 + t;
            int row = idx >> 3;
            int slot = idx & 7;
            GLOAD16(gA + (size_t)row * HD + kt * 64 + ((slot ^ (row & 7)) << 3),
                    &As[(i * 256 + (t & ~63)) * 8]);
        }
        #pragma unroll
        for (int i = 0; i < 4; ++i) {           // B: 128 c-rows x 64 k
            int idx = i * 256 + t;
            int c   = idx >> 3;
            int slot = idx & 7;
            int gr  = (c < 64) ? (n0 + c) : (ID + n0 + (c - 64));
            GLOAD16(gBt + (size_t)gr * HD + kt * 64 + ((slot ^ (c & 7)) << 3),
                    &Bs[(i * 256 + (t & ~63)) * 8]);
        }
        __syncthreads();

        #pragma unroll
        for (int ks = 0; ks < 64; ks += 32) {
            const int sl = (ks >> 3) + (lane >> 4);
            short8 av[4], bv[4];
            #pragma unroll
            for (int fm = 0; fm < 4; ++fm) {
                int row = wr * 64 + fm * 16 + (lane & 15);
                av[fm] = *(const short8*)&As[row * 64 + ((sl ^ (row & 7)) << 3)];
            }
            #pragma unroll
            for (int q = 0; q < 4; ++q) {
                int c = ((q < 2) ? 0 : 64) + wc * 32 + (q & 1) * 16 + (lane & 15);
                bv[q] = *(const short8*)&Bs[c * 64 + ((sl ^ (c & 7)) << 3)];
            }
            #pragma unroll
            for (int fm = 0; fm < 4; ++fm)
                #pragma unroll
                for (int q = 0; q < 4; ++q)
                    acc[fm][q] = __builtin_amdgcn_mfma_f32_16x16x32_bf16(av[fm], bv[q], acc[fm][q], 0, 0, 0);
        }
        __syncthreads();
    }

    // SwiGLU epilogue: gated = up * gate * sigmoid(gate) -> bf16 (chunk-local)
    unsigned short* g0 = gated + ((size_t)eL * TPE + m0) * ID;
    const int rq = (lane >> 4) << 2;   // C/D: row=(lane>>4)*4+r, col=lane&15 (m89)
    const int cl = lane & 15;
    #pragma unroll
    for (int fm = 0; fm < 4; ++fm) {
        #pragma unroll
        for (int fn = 0; fn < 2; ++fn) {
            f32x4 g = acc[fm][fn];
            f32x4 u = acc[fm][fn + 2];
            #pragma unroll
            for (int r = 0; r < 4; ++r) {
                float gv  = g[r];
                float val = u[r] * gv / (1.0f + __expf(-gv));
                int row = wr * 64 + fm * 16 + rq + r;
                int col = n0 + wc * 32 + fn * 16 + cl;
                g0[(size_t)row * ID + col] = f2b(val);
            }
        }
    }
}

// ---------------------------------------------------------------------------
// GEMM2: gated[eL](2048 x 4096 bf16) @ dwnT[eL](k-contig bf16) -> out fp32
// ---------------------------------------------------------------------------
__global__ __launch_bounds__(256) void k_gemm2(const unsigned short* __restrict__ gated,
                                               const unsigned short* __restrict__ dwnT,
                                               float* __restrict__ out,
                                               int e0)
{
    __shared__ unsigned short As[128 * 64];
    __shared__ unsigned short Bs[64 * 64];

    const int t    = threadIdx.x;
    const int lane = t & 63;
    const int w    = t >> 6;
    const int wr   = w >> 1;
    const int wc   = w & 1;
    const int eL   = blockIdx.z;
    const int e    = e0 + eL;
    const int n0   = blockIdx.x * 64;
    const int m0   = blockIdx.y * 128;

    const unsigned short* gA  = gated + ((size_t)eL * TPE + m0) * ID;
    const unsigned short* gBt = dwnT  + (size_t)eL * HD * ID;

    f32x4 acc[4][2];
    #pragma unroll
    for (int i = 0; i < 4; ++i)
        #pragma unroll
        for (int j = 0; j < 2; ++j)
            acc[i][j] = f32x4{0.f, 0.f, 0.f, 0.f};

    for (int kt = 0; kt < ID / 64; ++kt) {
        #pragma unroll
        for (int i = 0; i < 4; ++i) {           // A: 128 rows x 64 k (stride ID)
            int idx = i * 256 + t;
            int row = idx >> 3;
            int slot = idx & 7;
            GLOAD16(gA + (size_t)row * ID + kt * 64 + ((slot ^ (row & 7)) << 3),
                    &As[(i * 256 + (t & ~63)) * 8]);
        }
        #pragma unroll
        for (int i = 0; i < 2; ++i) {           // B: 64 c-rows x 64 k (stride ID)
            int idx = i * 256 + t;
            int c   = idx >> 3;
            int slot = idx & 7;
            GLOAD16(gBt + (size_t)(n0 + c) * ID + kt * 64 + ((slot ^ (c & 7)) << 3),
                    &Bs[(i * 256 + (t & ~63)) * 8]);
        }
        __syncthreads();

        #pragma unroll
        for (int ks = 0; ks < 64; ks += 32) {
            const int sl = (ks >> 3) + (lane >> 4);
            short8 av[4], bv[2];
            #pragma unroll
            for (int fm = 0; fm < 4; ++fm) {
                int row = wr * 64 + fm * 16 + (lane & 15);
                av[fm] = *(const short8*)&As[row * 64 + ((sl ^ (row & 7)) << 3)];
            }
            #pragma unroll
            for (int q = 0; q < 2; ++q) {
                int c = wc * 32 + q * 16 + (lane & 15);
                bv[q] = *(const short8*)&Bs[c * 64 + ((sl ^ (c & 7)) << 3)];
            }
            #pragma unroll
            for (int fm = 0; fm < 4; ++fm)
                #pragma unroll
                for (int q = 0; q < 2; ++q)
                    acc[fm][q] = __builtin_amdgcn_mfma_f32_16x16x32_bf16(av[fm], bv[q], acc[fm][q], 0, 0, 0);
        }
        __syncthreads();
    }

    float* o0 = out + (size_t)(e * TPE + m0) * HD;
    const int rq = (lane >> 4) << 2;
    const int cl = lane & 15;
    #pragma unroll
    for (int fm = 0; fm < 4; ++fm) {
        #pragma unroll
        for (int fn = 0; fn < 2; ++fn) {
            #pragma unroll
            for (int r = 0; r < 4; ++r) {
                int row = wr * 64 + fm * 16 + rq + r;
                int col = n0 + wc * 32 + fn * 16 + cl;
                o0[(size_t)row * HD + col] = acc[fm][fn][r];
            }
        }
    }
}

extern "C" void kernel_launch(void* const* d_in, const int* in_sizes, int n_in,
                              void* d_out, int out_size, void* d_ws, size_t ws_size,
                              hipStream_t stream)
{
    (void)in_sizes; (void)n_in; (void)out_size;
    const float* hs  = (const float*)d_in[0];
    const float* gup = (const float*)d_in[1];
    const float* dwn = (const float*)d_in[2];
    float* out = (float*)d_out;

    const size_t SZ_HSB   = (size_t)TOKENS * HD * 2;          // 67.1 MB
    const size_t SZ_GUPT  = (size_t)2 * ID * HD * 2;          // 16.78 MB / expert
    const size_t SZ_DWNT  = (size_t)HD * ID * 2;              //  8.39 MB / expert
    const size_t SZ_GATED = (size_t)TPE * ID * 2;             // 16.78 MB / expert
    const size_t perExp   = SZ_GUPT + SZ_DWNT + SZ_GATED;     // 41.94 MB

    int G = (ws_size > SZ_HSB) ? (int)((ws_size - SZ_HSB) / perExp) : 1;
    if (G < 1) G = 1;
    if (G > NE) G = NE;

    unsigned short* hsB   = (unsigned short*)d_ws;
    unsigned short* gupT  = (unsigned short*)((char*)d_ws + SZ_HSB);
    unsigned short* dwnT  = (unsigned short*)((char*)d_ws + SZ_HSB + (size_t)G * SZ_GUPT);
    unsigned short* gated = (unsigned short*)((char*)d_ws + SZ_HSB + (size_t)G * (SZ_GUPT + SZ_DWNT));

    k_f2b<<<2048, 256, 0, stream>>>(hs, hsB, TOKENS * HD / 4);

    for (int e0 = 0; e0 < NE; e0 += G) {
        int ne = NE - e0;
        if (ne > G) ne = G;
        k_transpose<<<dim3((2 * ID) / 64, HD / 64, ne), 256, 0, stream>>>(gup, gupT, HD, 2 * ID, e0);
        k_transpose<<<dim3(HD / 64, ID / 64, ne), 256, 0, stream>>>(dwn, dwnT, ID, HD, e0);
        k_gemm1<<<dim3(ID / 64, TPE / 128, ne), 256, 0, stream>>>(hsB, gupT, gated, e0);
        k_gemm2<<<dim3(HD / 64, TPE / 128, ne), 256, 0, stream>>>(gated, dwnT, out, e0);
    }
}

// Round 4
// 1173.417 us; speedup vs baseline: 1.5525x; 1.2446x over previous
//
#include <hip/hip_runtime.h>
#include <hip/hip_bf16.h>
#include <cstdint>
#include <cstddef>

#define NE  16
#define HD  1024
#define ID  4096
#define TPE 2048
#define TOKENS 32768

typedef __attribute__((ext_vector_type(8))) short short8;     // 8 bf16 (4 VGPRs)
typedef __attribute__((ext_vector_type(4))) float f32x4;      // MFMA acc
typedef __attribute__((ext_vector_type(4))) unsigned short u16x4;
typedef __attribute__((ext_vector_type(8))) unsigned short u16x8;

static __device__ __forceinline__ unsigned short f2b(float f) {
    __bf16 h = (__bf16)f;                       // RNE fp32->bf16
    return __builtin_bit_cast(unsigned short, h);
}

// wave-level async global->LDS, 16B/lane: LDS dest = uniform base + lane*16
// (linear). Swizzle applied on the GLOBAL source (rule #21).
#define GLOAD16(gsrc, ldsbase)                                                  \
    __builtin_amdgcn_global_load_lds(                                           \
        (const __attribute__((address_space(1))) unsigned int*)(gsrc),          \
        (__attribute__((address_space(3))) unsigned int*)(ldsbase), 16, 0, 0)

#define MFMA16(a, b, c) __builtin_amdgcn_mfma_f32_16x16x32_bf16((a), (b), (c), 0, 0, 0)

// ---------------------------------------------------------------------------
// Pre-pass 1: hs fp32 -> bf16 (linear)
// ---------------------------------------------------------------------------
__global__ void k_f2b(const float* __restrict__ src, unsigned short* __restrict__ dst, int n4)
{
    int i = blockIdx.x * blockDim.x + threadIdx.x;
    int stride = gridDim.x * blockDim.x;
    for (; i < n4; i += stride) {
        float4 v = *(const float4*)(src + (size_t)i * 4);
        u16x4 b = { f2b(v.x), f2b(v.y), f2b(v.z), f2b(v.w) };
        *(u16x4*)(dst + (size_t)i * 4) = b;
    }
}

// ---------------------------------------------------------------------------
// Pre-pass 2: weight convert+transpose. src fp32 [e][K][N] (global e),
// dst bf16 [eL][N][K] (chunk-local). 64x64 tiles via LDS.
// ---------------------------------------------------------------------------
__global__ __launch_bounds__(256) void k_transpose(const float* __restrict__ src,
                                                   unsigned short* __restrict__ dst,
                                                   int K, int N, int e0)
{
    __shared__ unsigned short LT[64][72];
    const int t  = threadIdx.x;
    const int eL = blockIdx.z;
    const float* s = src + (size_t)(e0 + eL) * K * N
                         + (size_t)(blockIdx.y * 64) * N + blockIdx.x * 64;
    unsigned short* d = dst + (size_t)eL * N * K
                            + (size_t)(blockIdx.x * 64) * K + blockIdx.y * 64;
    #pragma unroll
    for (int i = 0; i < 4; ++i) {
        int row = i * 16 + (t >> 4);
        int c4  = (t & 15) * 4;
        float4 v = *(const float4*)(s + (size_t)row * N + c4);
        LT[c4 + 0][row] = f2b(v.x);
        LT[c4 + 1][row] = f2b(v.y);
        LT[c4 + 2][row] = f2b(v.z);
        LT[c4 + 3][row] = f2b(v.w);
    }
    __syncthreads();
    #pragma unroll
    for (int i = 0; i < 2; ++i) {
        int n  = i * 32 + (t >> 3);
        int k8 = (t & 7) * 8;
        u16x8 v = *(const u16x8*)&LT[n][k8];
        *(u16x8*)(d + (size_t)n * K + k8) = v;
    }
}

// ---------------------------------------------------------------------------
// GEMM1 + SwiGLU, 256x256 tile, 8 waves, counted-vmcnt double-buffer (T3/T4/T5).
// A: 256 M-rows; B: 256 rows = gate/up interleaved in 32-col groups so each
// wave's fn0,1 (gate) pairs with fn2,3 (up) at the same output columns.
// Gated output per block: 256 x 128.
// ---------------------------------------------------------------------------
__global__ __launch_bounds__(512, 2) void k_gemm1(const unsigned short* __restrict__ hsB,
                                                  const unsigned short* __restrict__ gupT,
                                                  unsigned short* __restrict__ gated,
                                                  int e0)
{
    __shared__ unsigned short As[2][256 * 64];
    __shared__ unsigned short Bs[2][256 * 64];
    const int NT = HD / 64;   // 16

    const int t    = threadIdx.x;
    const int lane = t & 63;
    const int w    = t >> 6;
    const int wr   = w >> 2;          // 0..1
    const int wc   = w & 3;           // 0..3
    const int eL   = blockIdx.z;
    const int e    = e0 + eL;
    const int n0g  = blockIdx.x * 128;   // gated col base
    const int m0   = blockIdx.y * 256;

    const unsigned short* gA  = hsB  + (size_t)(e * TPE + m0) * HD;
    const unsigned short* gBt = gupT + (size_t)eL * (2 * ID) * HD;

    f32x4 acc[8][4];
    #pragma unroll
    for (int i = 0; i < 8; ++i)
        #pragma unroll
        for (int j = 0; j < 4; ++j)
            acc[i][j] = f32x4{0.f, 0.f, 0.f, 0.f};

    auto STAGE = [&](int buf, int kt) {
        #pragma unroll
        for (int i = 0; i < 4; ++i) {              // A: 256 rows x 64 k
            int idx = i * 512 + t;
            int row = idx >> 3, sl = idx & 7;
            GLOAD16(gA + (size_t)row * HD + kt * 64 + ((sl ^ (row & 7)) << 3),
                    &As[buf][(size_t)(i * 512 + (t & ~63)) * 8]);
        }
        #pragma unroll
        for (int i = 0; i < 4; ++i) {              // B: 256 rows (gate/up x32 groups)
            int idx = i * 512 + t;
            int c = idx >> 3, sl = idx & 7;
            int g = c >> 5, j = c & 31;
            int grow = ((g & 1) ? ID : 0) + n0g + ((g >> 1) << 5) + j;
            GLOAD16(gBt + (size_t)grow * HD + kt * 64 + ((sl ^ (c & 7)) << 3),
                    &Bs[buf][(size_t)(i * 512 + (t & ~63)) * 8]);
        }
    };

    STAGE(0, 0);
    STAGE(1, 1);
    asm volatile("s_waitcnt vmcnt(8)" ::: "memory");
    __builtin_amdgcn_s_barrier();

    for (int kt = 0; kt < NT; ++kt) {
        const int cur = kt & 1;
        const unsigned short* Ab = &As[cur][0];
        const unsigned short* Bb = &Bs[cur][0];

        // ---- ks0 fragments + MFMAs ----
        short8 av[8], bv[4];
        #pragma unroll
        for (int fm = 0; fm < 8; ++fm) {
            int row = wr * 128 + fm * 16 + (lane & 15);
            int sl  = (lane >> 4);
            av[fm] = *(const short8*)&Ab[row * 64 + ((sl ^ (row & 7)) << 3)];
        }
        #pragma unroll
        for (int fn = 0; fn < 4; ++fn) {
            int c  = wc * 64 + fn * 16 + (lane & 15);
            int sl = (lane >> 4);
            bv[fn] = *(const short8*)&Bb[c * 64 + ((sl ^ (c & 7)) << 3)];
        }
        __builtin_amdgcn_s_setprio(1);
        #pragma unroll
        for (int fm = 0; fm < 8; ++fm)
            #pragma unroll
            for (int fn = 0; fn < 4; ++fn)
                acc[fm][fn] = MFMA16(av[fm], bv[fn], acc[fm][fn]);
        __builtin_amdgcn_s_setprio(0);

        // ---- ks1 fragments (reads overlap ks0 MFMAs via compiler sched) ----
        short8 av1[8], bv1[4];
        #pragma unroll
        for (int fm = 0; fm < 8; ++fm) {
            int row = wr * 128 + fm * 16 + (lane & 15);
            int sl  = 4 + (lane >> 4);
            av1[fm] = *(const short8*)&Ab[row * 64 + ((sl ^ (row & 7)) << 3)];
        }
        #pragma unroll
        for (int fn = 0; fn < 4; ++fn) {
            int c  = wc * 64 + fn * 16 + (lane & 15);
            int sl = 4 + (lane >> 4);
            bv1[fn] = *(const short8*)&Bb[c * 64 + ((sl ^ (c & 7)) << 3)];
        }
        asm volatile("s_waitcnt lgkmcnt(0)" ::: "memory");
        __builtin_amdgcn_sched_barrier(0);
        __builtin_amdgcn_s_barrier();            // all reads of P[cur] complete
        if (kt + 2 < NT) {
            STAGE(cur, kt + 2);                  // overwrite just-freed buffer
            asm volatile("s_waitcnt vmcnt(8)" ::: "memory");  // kt+1 landed; kt+2 in flight
        } else {
            asm volatile("s_waitcnt vmcnt(0)" ::: "memory");
        }
        __builtin_amdgcn_s_barrier();            // P[cur^1] visible to all waves
        __builtin_amdgcn_s_setprio(1);
        #pragma unroll
        for (int fm = 0; fm < 8; ++fm)
            #pragma unroll
            for (int fn = 0; fn < 4; ++fn)
                acc[fm][fn] = MFMA16(av1[fm], bv1[fn], acc[fm][fn]);
        __builtin_amdgcn_s_setprio(0);
    }

    // ---- SwiGLU epilogue: fn (gate) pairs with fn+2 (up), same cols ----
    unsigned short* g0 = gated + ((size_t)eL * TPE + m0) * ID;
    const int rq = (lane >> 4) << 2;   // C/D: row=(lane>>4)*4+r, col=lane&15 (m89)
    const int cl = lane & 15;
    #pragma unroll
    for (int fm = 0; fm < 8; ++fm) {
        #pragma unroll
        for (int fp = 0; fp < 2; ++fp) {
            f32x4 g = acc[fm][fp];
            f32x4 u = acc[fm][fp + 2];
            #pragma unroll
            for (int r = 0; r < 4; ++r) {
                float gv  = g[r];
                float val = u[r] * gv / (1.0f + __expf(-gv));
                int row = wr * 128 + fm * 16 + rq + r;
                int col = n0g + wc * 32 + fp * 16 + cl;
                g0[(size_t)row * ID + col] = f2b(val);
            }
        }
    }
}

// ---------------------------------------------------------------------------
// GEMM2: gated (bf16, k-contig) @ dwnT (bf16, k-contig) -> out fp32.
// 256x256 tile, same pipeline.
// ---------------------------------------------------------------------------
__global__ __launch_bounds__(512, 2) void k_gemm2(const unsigned short* __restrict__ gated,
                                                  const unsigned short* __restrict__ dwnT,
                                                  float* __restrict__ out,
                                                  int e0)
{
    __shared__ unsigned short As[2][256 * 64];
    __shared__ unsigned short Bs[2][256 * 64];
    const int NT = ID / 64;   // 64

    const int t    = threadIdx.x;
    const int lane = t & 63;
    const int w    = t >> 6;
    const int wr   = w >> 2;
    const int wc   = w & 3;
    const int eL   = blockIdx.z;
    const int e    = e0 + eL;
    const int n0   = blockIdx.x * 256;
    const int m0   = blockIdx.y * 256;

    const unsigned short* gA  = gated + ((size_t)eL * TPE + m0) * ID;
    const unsigned short* gBt = dwnT  + (size_t)eL * HD * ID;

    f32x4 acc[8][4];
    #pragma unroll
    for (int i = 0; i < 8; ++i)
        #pragma unroll
        for (int j = 0; j < 4; ++j)
            acc[i][j] = f32x4{0.f, 0.f, 0.f, 0.f};

    auto STAGE = [&](int buf, int kt) {
        #pragma unroll
        for (int i = 0; i < 4; ++i) {
            int idx = i * 512 + t;
            int row = idx >> 3, sl = idx & 7;
            GLOAD16(gA + (size_t)row * ID + kt * 64 + ((sl ^ (row & 7)) << 3),
                    &As[buf][(size_t)(i * 512 + (t & ~63)) * 8]);
        }
        #pragma unroll
        for (int i = 0; i < 4; ++i) {
            int idx = i * 512 + t;
            int c = idx >> 3, sl = idx & 7;
            GLOAD16(gBt + (size_t)(n0 + c) * ID + kt * 64 + ((sl ^ (c & 7)) << 3),
                    &Bs[buf][(size_t)(i * 512 + (t & ~63)) * 8]);
        }
    };

    STAGE(0, 0);
    STAGE(1, 1);
    asm volatile("s_waitcnt vmcnt(8)" ::: "memory");
    __builtin_amdgcn_s_barrier();

    for (int kt = 0; kt < NT; ++kt) {
        const int cur = kt & 1;
        const unsigned short* Ab = &As[cur][0];
        const unsigned short* Bb = &Bs[cur][0];

        short8 av[8], bv[4];
        #pragma unroll
        for (int fm = 0; fm < 8; ++fm) {
            int row = wr * 128 + fm * 16 + (lane & 15);
            int sl  = (lane >> 4);
            av[fm] = *(const short8*)&Ab[row * 64 + ((sl ^ (row & 7)) << 3)];
        }
        #pragma unroll
        for (int fn = 0; fn < 4; ++fn) {
            int c  = wc * 64 + fn * 16 + (lane & 15);
            int sl = (lane >> 4);
            bv[fn] = *(const short8*)&Bb[c * 64 + ((sl ^ (c & 7)) << 3)];
        }
        __builtin_amdgcn_s_setprio(1);
        #pragma unroll
        for (int fm = 0; fm < 8; ++fm)
            #pragma unroll
            for (int fn = 0; fn < 4; ++fn)
                acc[fm][fn] = MFMA16(av[fm], bv[fn], acc[fm][fn]);
        __builtin_amdgcn_s_setprio(0);

        short8 av1[8], bv1[4];
        #pragma unroll
        for (int fm = 0; fm < 8; ++fm) {
            int row = wr * 128 + fm * 16 + (lane & 15);
            int sl  = 4 + (lane >> 4);
            av1[fm] = *(const short8*)&Ab[row * 64 + ((sl ^ (row & 7)) << 3)];
        }
        #pragma unroll
        for (int fn = 0; fn < 4; ++fn) {
            int c  = wc * 64 + fn * 16 + (lane & 15);
            int sl = 4 + (lane >> 4);
            bv1[fn] = *(const short8*)&Bb[c * 64 + ((sl ^ (c & 7)) << 3)];
        }
        asm volatile("s_waitcnt lgkmcnt(0)" ::: "memory");
        __builtin_amdgcn_sched_barrier(0);
        __builtin_amdgcn_s_barrier();
        if (kt + 2 < NT) {
            STAGE(cur, kt + 2);
            asm volatile("s_waitcnt vmcnt(8)" ::: "memory");
        } else {
            asm volatile("s_waitcnt vmcnt(0)" ::: "memory");
        }
        __builtin_amdgcn_s_barrier();
        __builtin_amdgcn_s_setprio(1);
        #pragma unroll
        for (int fm = 0; fm < 8; ++fm)
            #pragma unroll
            for (int fn = 0; fn < 4; ++fn)
                acc[fm][fn] = MFMA16(av1[fm], bv1[fn], acc[fm][fn]);
        __builtin_amdgcn_s_setprio(0);
    }

    float* o0 = out + (size_t)(e * TPE + m0) * HD;
    const int rq = (lane >> 4) << 2;
    const int cl = lane & 15;
    #pragma unroll
    for (int fm = 0; fm < 8; ++fm) {
        #pragma unroll
        for (int fn = 0; fn < 4; ++fn) {
            #pragma unroll
            for (int r = 0; r < 4; ++r) {
                int row = wr * 128 + fm * 16 + rq + r;
                int col = n0 + wc * 64 + fn * 16 + cl;
                o0[(size_t)row * HD + col] = acc[fm][fn][r];
            }
        }
    }
}

extern "C" void kernel_launch(void* const* d_in, const int* in_sizes, int n_in,
                              void* d_out, int out_size, void* d_ws, size_t ws_size,
                              hipStream_t stream)
{
    (void)in_sizes; (void)n_in; (void)out_size;
    const float* hs  = (const float*)d_in[0];
    const float* gup = (const float*)d_in[1];
    const float* dwn = (const float*)d_in[2];
    float* out = (float*)d_out;

    const size_t SZ_HSB   = (size_t)TOKENS * HD * 2;          // 67.1 MB
    const size_t SZ_GUPT  = (size_t)2 * ID * HD * 2;          // 16.78 MB / expert
    const size_t SZ_DWNT  = (size_t)HD * ID * 2;              //  8.39 MB / expert
    const size_t SZ_GATED = (size_t)TPE * ID * 2;             // 16.78 MB / expert
    const size_t perExp   = SZ_GUPT + SZ_DWNT + SZ_GATED;     // 41.94 MB

    int G = (ws_size > SZ_HSB) ? (int)((ws_size - SZ_HSB) / perExp) : 1;
    if (G < 1) G = 1;
    if (G > NE) G = NE;

    unsigned short* hsB   = (unsigned short*)d_ws;
    unsigned short* gupT  = (unsigned short*)((char*)d_ws + SZ_HSB);
    unsigned short* dwnT  = (unsigned short*)((char*)d_ws + SZ_HSB + (size_t)G * SZ_GUPT);
    unsigned short* gated = (unsigned short*)((char*)d_ws + SZ_HSB + (size_t)G * (SZ_GUPT + SZ_DWNT));

    k_f2b<<<2048, 256, 0, stream>>>(hs, hsB, TOKENS * HD / 4);

    for (int e0 = 0; e0 < NE; e0 += G) {
        int ne = NE - e0;
        if (ne > G) ne = G;
        k_transpose<<<dim3((2 * ID) / 64, HD / 64, ne), 256, 0, stream>>>(gup, gupT, HD, 2 * ID, e0);
        k_transpose<<<dim3(HD / 64, ID / 64, ne), 256, 0, stream>>>(dwn, dwnT, ID, HD, e0);
        k_gemm1<<<dim3(ID / 128, TPE / 256, ne), 512, 0, stream>>>(hsB, gupT, gated, e0);
        k_gemm2<<<dim3(HD / 256, TPE / 256, ne), 512, 0, stream>>>(gated, dwnT, out, e0);
    }
}

// Round 5
// 1149.614 us; speedup vs baseline: 1.5847x; 1.0207x over previous
//
#include <hip/hip_runtime.h>
#include <hip/hip_bf16.h>
#include <cstdint>
#include <cstddef>

#define NE  16
#define HD  1024
#define ID  4096
#define TPE 2048
#define TOKENS 32768

typedef __attribute__((ext_vector_type(8))) short short8;     // 8 bf16 (4 VGPRs)
typedef __attribute__((ext_vector_type(4))) float f32x4;      // MFMA acc
typedef __attribute__((ext_vector_type(4))) unsigned short u16x4;
typedef __attribute__((ext_vector_type(8))) unsigned short u16x8;

static __device__ __forceinline__ unsigned short f2b(float f) {
    __bf16 h = (__bf16)f;                       // RNE fp32->bf16
    return __builtin_bit_cast(unsigned short, h);
}

// wave-level async global->LDS, 16B/lane: LDS dest = uniform base + lane*16
// (linear). Swizzle applied on the GLOBAL source (rule #21).
#define GLOAD16(gsrc, ldsbase)                                                  \
    __builtin_amdgcn_global_load_lds(                                           \
        (const __attribute__((address_space(1))) unsigned int*)(gsrc),          \
        (__attribute__((address_space(3))) unsigned int*)(ldsbase), 16, 0, 0)

#define MFMA16(a, b, c) __builtin_amdgcn_mfma_f32_16x16x32_bf16((a), (b), (c), 0, 0, 0)

// ---------------------------------------------------------------------------
// Pre-pass 1: hs fp32 -> bf16 (linear)
// ---------------------------------------------------------------------------
__global__ void k_f2b(const float* __restrict__ src, unsigned short* __restrict__ dst, int n4)
{
    int i = blockIdx.x * blockDim.x + threadIdx.x;
    int stride = gridDim.x * blockDim.x;
    for (; i < n4; i += stride) {
        float4 v = *(const float4*)(src + (size_t)i * 4);
        u16x4 b = { f2b(v.x), f2b(v.y), f2b(v.z), f2b(v.w) };
        *(u16x4*)(dst + (size_t)i * 4) = b;
    }
}

// ---------------------------------------------------------------------------
// Pre-pass 2: weight convert+transpose. src fp32 [e][K][N] (global e),
// dst bf16 [eL][N][K] (chunk-local). 64x64 tiles via LDS.
// ---------------------------------------------------------------------------
__global__ __launch_bounds__(256) void k_transpose(const float* __restrict__ src,
                                                   unsigned short* __restrict__ dst,
                                                   int K, int N, int e0)
{
    __shared__ unsigned short LT[64][72];
    const int t  = threadIdx.x;
    const int eL = blockIdx.z;
    const float* s = src + (size_t)(e0 + eL) * K * N
                         + (size_t)(blockIdx.y * 64) * N + blockIdx.x * 64;
    unsigned short* d = dst + (size_t)eL * N * K
                            + (size_t)(blockIdx.x * 64) * K + blockIdx.y * 64;
    #pragma unroll
    for (int i = 0; i < 4; ++i) {
        int row = i * 16 + (t >> 4);
        int c4  = (t & 15) * 4;
        float4 v = *(const float4*)(s + (size_t)row * N + c4);
        LT[c4 + 0][row] = f2b(v.x);
        LT[c4 + 1][row] = f2b(v.y);
        LT[c4 + 2][row] = f2b(v.z);
        LT[c4 + 3][row] = f2b(v.w);
    }
    __syncthreads();
    #pragma unroll
    for (int i = 0; i < 2; ++i) {
        int n  = i * 32 + (t >> 3);
        int k8 = (t & 7) * 8;
        u16x8 v = *(const u16x8*)&LT[n][k8];
        *(u16x8*)(d + (size_t)n * K + k8) = v;
    }
}

// ---------------------------------------------------------------------------
// GEMM1 + SwiGLU, 256x256 tile, 8 waves, counted-vmcnt double-buffer.
// Wait discipline (T4): tile-kt readiness is awaited at the TOP of iter kt
// (issued ~1.5 iters earlier -> HBM latency covered); stage of kt+2 issues
// mid-iteration right after the read-release barrier and is NOT awaited in
// this iteration. vmcnt never drains to 0 in steady state.
// ---------------------------------------------------------------------------
__global__ __launch_bounds__(512, 2) void k_gemm1(const unsigned short* __restrict__ hsB,
                                                  const unsigned short* __restrict__ gupT,
                                                  unsigned short* __restrict__ gated,
                                                  int e0)
{
    __shared__ unsigned short As[2][256 * 64];
    __shared__ unsigned short Bs[2][256 * 64];
    const int NT = HD / 64;   // 16

    const int t    = threadIdx.x;
    const int lane = t & 63;
    const int w    = t >> 6;
    const int wr   = w >> 2;          // 0..1
    const int wc   = w & 3;           // 0..3
    const int eL   = blockIdx.z;
    const int e    = e0 + eL;
    const int n0g  = blockIdx.x * 128;   // gated col base
    const int m0   = blockIdx.y * 256;

    const unsigned short* gA  = hsB  + (size_t)(e * TPE + m0) * HD;
    const unsigned short* gBt = gupT + (size_t)eL * (2 * ID) * HD;

    f32x4 acc[8][4];
    #pragma unroll
    for (int i = 0; i < 8; ++i)
        #pragma unroll
        for (int j = 0; j < 4; ++j)
            acc[i][j] = f32x4{0.f, 0.f, 0.f, 0.f};

    auto STAGE = [&](int buf, int kt) {
        #pragma unroll
        for (int i = 0; i < 4; ++i) {              // A: 256 rows x 64 k
            int idx = i * 512 + t;
            int row = idx >> 3, sl = idx & 7;
            GLOAD16(gA + (size_t)row * HD + kt * 64 + ((sl ^ (row & 7)) << 3),
                    &As[buf][(size_t)(i * 512 + (t & ~63)) * 8]);
        }
        #pragma unroll
        for (int i = 0; i < 4; ++i) {              // B: 256 rows (gate/up x32 groups)
            int idx = i * 512 + t;
            int c = idx >> 3, sl = idx & 7;
            int g = c >> 5, j = c & 31;
            int grow = ((g & 1) ? ID : 0) + n0g + ((g >> 1) << 5) + j;
            GLOAD16(gBt + (size_t)grow * HD + kt * 64 + ((sl ^ (c & 7)) << 3),
                    &Bs[buf][(size_t)(i * 512 + (t & ~63)) * 8]);
        }
    };

    STAGE(0, 0);
    STAGE(1, 1);

    for (int kt = 0; kt < NT; ++kt) {
        const int cur = kt & 1;
        const unsigned short* Ab = &As[cur][0];
        const unsigned short* Bb = &Bs[cur][0];

        // ---- top wait: tile kt resident (issued >=1.5 iters ago) ----
        if (kt < NT - 1) { asm volatile("s_waitcnt vmcnt(8)" ::: "memory"); }
        else             { asm volatile("s_waitcnt vmcnt(0)" ::: "memory"); }
        __builtin_amdgcn_s_barrier();

        // ---- ks0 fragments + MFMAs (ks1 reads interleave under these) ----
        short8 av[8], bv[4];
        #pragma unroll
        for (int fm = 0; fm < 8; ++fm) {
            int row = wr * 128 + fm * 16 + (lane & 15);
            int sl  = (lane >> 4);
            av[fm] = *(const short8*)&Ab[row * 64 + ((sl ^ (row & 7)) << 3)];
        }
        #pragma unroll
        for (int fn = 0; fn < 4; ++fn) {
            int c  = wc * 64 + fn * 16 + (lane & 15);
            int sl = (lane >> 4);
            bv[fn] = *(const short8*)&Bb[c * 64 + ((sl ^ (c & 7)) << 3)];
        }
        __builtin_amdgcn_s_setprio(1);
        #pragma unroll
        for (int fm = 0; fm < 8; ++fm)
            #pragma unroll
            for (int fn = 0; fn < 4; ++fn)
                acc[fm][fn] = MFMA16(av[fm], bv[fn], acc[fm][fn]);
        __builtin_amdgcn_s_setprio(0);

        // ---- ks1 fragments ----
        short8 av1[8], bv1[4];
        #pragma unroll
        for (int fm = 0; fm < 8; ++fm) {
            int row = wr * 128 + fm * 16 + (lane & 15);
            int sl  = 4 + (lane >> 4);
            av1[fm] = *(const short8*)&Ab[row * 64 + ((sl ^ (row & 7)) << 3)];
        }
        #pragma unroll
        for (int fn = 0; fn < 4; ++fn) {
            int c  = wc * 64 + fn * 16 + (lane & 15);
            int sl = 4 + (lane >> 4);
            bv1[fn] = *(const short8*)&Bb[c * 64 + ((sl ^ (c & 7)) << 3)];
        }
        asm volatile("s_waitcnt lgkmcnt(0)" ::: "memory");
        __builtin_amdgcn_sched_barrier(0);
        __builtin_amdgcn_s_barrier();            // all waves done reading P[cur]
        if (kt + 2 < NT)
            STAGE(cur, kt + 2);                  // overwrite freed buffer; NO wait here
        __builtin_amdgcn_s_setprio(1);
        #pragma unroll
        for (int fm = 0; fm < 8; ++fm)
            #pragma unroll
            for (int fn = 0; fn < 4; ++fn)
                acc[fm][fn] = MFMA16(av1[fm], bv1[fn], acc[fm][fn]);
        __builtin_amdgcn_s_setprio(0);
    }

    // ---- SwiGLU epilogue: fn (gate) pairs with fn+2 (up), same cols ----
    unsigned short* g0 = gated + ((size_t)eL * TPE + m0) * ID;
    const int rq = (lane >> 4) << 2;   // C/D: row=(lane>>4)*4+r, col=lane&15 (m89)
    const int cl = lane & 15;
    #pragma unroll
    for (int fm = 0; fm < 8; ++fm) {
        #pragma unroll
        for (int fp = 0; fp < 2; ++fp) {
            f32x4 g = acc[fm][fp];
            f32x4 u = acc[fm][fp + 2];
            #pragma unroll
            for (int r = 0; r < 4; ++r) {
                float gv  = g[r];
                float val = u[r] * gv / (1.0f + __expf(-gv));
                int row = wr * 128 + fm * 16 + rq + r;
                int col = n0g + wc * 32 + fp * 16 + cl;
                g0[(size_t)row * ID + col] = f2b(val);
            }
        }
    }
}

// ---------------------------------------------------------------------------
// GEMM2: gated (bf16, k-contig) @ dwnT (bf16, k-contig) -> out fp32.
// 256x256 tile, same pipeline & wait discipline.
// ---------------------------------------------------------------------------
__global__ __launch_bounds__(512, 2) void k_gemm2(const unsigned short* __restrict__ gated,
                                                  const unsigned short* __restrict__ dwnT,
                                                  float* __restrict__ out,
                                                  int e0)
{
    __shared__ unsigned short As[2][256 * 64];
    __shared__ unsigned short Bs[2][256 * 64];
    const int NT = ID / 64;   // 64

    const int t    = threadIdx.x;
    const int lane = t & 63;
    const int w    = t >> 6;
    const int wr   = w >> 2;
    const int wc   = w & 3;
    const int eL   = blockIdx.z;
    const int e    = e0 + eL;
    const int n0   = blockIdx.x * 256;
    const int m0   = blockIdx.y * 256;

    const unsigned short* gA  = gated + ((size_t)eL * TPE + m0) * ID;
    const unsigned short* gBt = dwnT  + (size_t)eL * HD * ID;

    f32x4 acc[8][4];
    #pragma unroll
    for (int i = 0; i < 8; ++i)
        #pragma unroll
        for (int j = 0; j < 4; ++j)
            acc[i][j] = f32x4{0.f, 0.f, 0.f, 0.f};

    auto STAGE = [&](int buf, int kt) {
        #pragma unroll
        for (int i = 0; i < 4; ++i) {
            int idx = i * 512 + t;
            int row = idx >> 3, sl = idx & 7;
            GLOAD16(gA + (size_t)row * ID + kt * 64 + ((sl ^ (row & 7)) << 3),
                    &As[buf][(size_t)(i * 512 + (t & ~63)) * 8]);
        }
        #pragma unroll
        for (int i = 0; i < 4; ++i) {
            int idx = i * 512 + t;
            int c = idx >> 3, sl = idx & 7;
            GLOAD16(gBt + (size_t)(n0 + c) * ID + kt * 64 + ((sl ^ (c & 7)) << 3),
                    &Bs[buf][(size_t)(i * 512 + (t & ~63)) * 8]);
        }
    };

    STAGE(0, 0);
    STAGE(1, 1);

    for (int kt = 0; kt < NT; ++kt) {
        const int cur = kt & 1;
        const unsigned short* Ab = &As[cur][0];
        const unsigned short* Bb = &Bs[cur][0];

        if (kt < NT - 1) { asm volatile("s_waitcnt vmcnt(8)" ::: "memory"); }
        else             { asm volatile("s_waitcnt vmcnt(0)" ::: "memory"); }
        __builtin_amdgcn_s_barrier();

        short8 av[8], bv[4];
        #pragma unroll
        for (int fm = 0; fm < 8; ++fm) {
            int row = wr * 128 + fm * 16 + (lane & 15);
            int sl  = (lane >> 4);
            av[fm] = *(const short8*)&Ab[row * 64 + ((sl ^ (row & 7)) << 3)];
        }
        #pragma unroll
        for (int fn = 0; fn < 4; ++fn) {
            int c  = wc * 64 + fn * 16 + (lane & 15);
            int sl = (lane >> 4);
            bv[fn] = *(const short8*)&Bb[c * 64 + ((sl ^ (c & 7)) << 3)];
        }
        __builtin_amdgcn_s_setprio(1);
        #pragma unroll
        for (int fm = 0; fm < 8; ++fm)
            #pragma unroll
            for (int fn = 0; fn < 4; ++fn)
                acc[fm][fn] = MFMA16(av[fm], bv[fn], acc[fm][fn]);
        __builtin_amdgcn_s_setprio(0);

        short8 av1[8], bv1[4];
        #pragma unroll
        for (int fm = 0; fm < 8; ++fm) {
            int row = wr * 128 + fm * 16 + (lane & 15);
            int sl  = 4 + (lane >> 4);
            av1[fm] = *(const short8*)&Ab[row * 64 + ((sl ^ (row & 7)) << 3)];
        }
        #pragma unroll
        for (int fn = 0; fn < 4; ++fn) {
            int c  = wc * 64 + fn * 16 + (lane & 15);
            int sl = 4 + (lane >> 4);
            bv1[fn] = *(const short8*)&Bb[c * 64 + ((sl ^ (c & 7)) << 3)];
        }
        asm volatile("s_waitcnt lgkmcnt(0)" ::: "memory");
        __builtin_amdgcn_sched_barrier(0);
        __builtin_amdgcn_s_barrier();
        if (kt + 2 < NT)
            STAGE(cur, kt + 2);
        __builtin_amdgcn_s_setprio(1);
        #pragma unroll
        for (int fm = 0; fm < 8; ++fm)
            #pragma unroll
            for (int fn = 0; fn < 4; ++fn)
                acc[fm][fn] = MFMA16(av1[fm], bv1[fn], acc[fm][fn]);
        __builtin_amdgcn_s_setprio(0);
    }

    float* o0 = out + (size_t)(e * TPE + m0) * HD;
    const int rq = (lane >> 4) << 2;
    const int cl = lane & 15;
    #pragma unroll
    for (int fm = 0; fm < 8; ++fm) {
        #pragma unroll
        for (int fn = 0; fn < 4; ++fn) {
            #pragma unroll
            for (int r = 0; r < 4; ++r) {
                int row = wr * 128 + fm * 16 + rq + r;
                int col = n0 + wc * 64 + fn * 16 + cl;
                o0[(size_t)row * HD + col] = acc[fm][fn][r];
            }
        }
    }
}

extern "C" void kernel_launch(void* const* d_in, const int* in_sizes, int n_in,
                              void* d_out, int out_size, void* d_ws, size_t ws_size,
                              hipStream_t stream)
{
    (void)in_sizes; (void)n_in; (void)out_size;
    const float* hs  = (const float*)d_in[0];
    const float* gup = (const float*)d_in[1];
    const float* dwn = (const float*)d_in[2];
    float* out = (float*)d_out;

    const size_t SZ_HSB   = (size_t)TOKENS * HD * 2;          // 67.1 MB
    const size_t SZ_GUPT  = (size_t)2 * ID * HD * 2;          // 16.78 MB / expert
    const size_t SZ_DWNT  = (size_t)HD * ID * 2;              //  8.39 MB / expert
    const size_t SZ_GATED = (size_t)TPE * ID * 2;             // 16.78 MB / expert
    const size_t perExp   = SZ_GUPT + SZ_DWNT + SZ_GATED;     // 41.94 MB

    int G = (ws_size > SZ_HSB) ? (int)((ws_size - SZ_HSB) / perExp) : 1;
    if (G < 1) G = 1;
    if (G > NE) G = NE;

    unsigned short* hsB   = (unsigned short*)d_ws;
    unsigned short* gupT  = (unsigned short*)((char*)d_ws + SZ_HSB);
    unsigned short* dwnT  = (unsigned short*)((char*)d_ws + SZ_HSB + (size_t)G * SZ_GUPT);
    unsigned short* gated = (unsigned short*)((char*)d_ws + SZ_HSB + (size_t)G * (SZ_GUPT + SZ_DWNT));

    k_f2b<<<2048, 256, 0, stream>>>(hs, hsB, TOKENS * HD / 4);

    for (int e0 = 0; e0 < NE; e0 += G) {
        int ne = NE - e0;
        if (ne > G) ne = G;
        k_transpose<<<dim3((2 * ID) / 64, HD / 64, ne), 256, 0, stream>>>(gup, gupT, HD, 2 * ID, e0);
        k_transpose<<<dim3(HD / 64, ID / 64, ne), 256, 0, stream>>>(dwn, dwnT, ID, HD, e0);
        k_gemm1<<<dim3(ID / 128, TPE / 256, ne), 512, 0, stream>>>(hsB, gupT, gated, e0);
        k_gemm2<<<dim3(HD / 256, TPE / 256, ne), 512, 0, stream>>>(gated, dwnT, out, e0);
    }
}